// Round 19
// baseline (40.052 us; speedup 1.0000x reference)
//
#include <hip/hip_runtime.h>

// Smith-Waterman soft-DP, B=512, x: (512,151,151) f32, scalar output.
// ROW-SCAN formulation (150 rows), critical path minimized to ~13 hops/row:
// h0 in distributed-coefficient form (h0 = cA*C + cB, coefficients built
// off-path from the previous row's Q-sums and decoded x), 4-level weighted
// DPP scan (row_shr1, row_shr2, bcast15 w/ row_mask 0xa, bcast31; dropped
// levels contribute <= e^-12 relative). Lane packing c = 3*lane + k.
// Linear domain H = exp(h)*2^-E; x staged as e5m2 bytes row-major in LDS.
// 512 blocks x 256 threads; waves 1-3 stage then exit; wave 0 runs DP.

#define CGO 6.737946999085467e-03f   // e^-5
#define CGE 3.678794411714423e-01f   // e^-1
#define L2E 1.4426950408889634f
#define LN2 0.6931471805599453f
#define RTHR 0x1p28f
#define RSC  0x1p-64f
#define EADD 64.0f

#define K20 6.737946999085467e-03f   // CGO
#define K21 2.478752176666358e-03f   // CGO*CGE   = e^-6
#define K22 9.118819655545162e-04f   // CGO*CGE^2 = e^-7
#define CA1 3.678794411714423e-01f   // e^-1
#define CA2 1.353352832366127e-01f   // e^-2
#define CA3 4.978706836786394e-02f   // e^-3
#define SAW1 4.978706836786394e-02f  // A   = e^-3
#define SAW2 2.478752176666358e-03f  // A^2 = e^-6

#if __has_builtin(__builtin_amdgcn_exp2f)
#define EXP2(x) __builtin_amdgcn_exp2f(x)
#else
static __device__ __forceinline__ float EXP2_(float x){float r;asm("v_exp_f32 %0, %1":"=v"(r):"v"(x));return r;}
#define EXP2(x) EXP2_(x)
#endif

#if __has_builtin(__builtin_amdgcn_logf)
#define LOG2(x) __builtin_amdgcn_logf(x)
#else
static __device__ __forceinline__ float LOG2_(float x){float r;asm("v_log_f32 %0, %1":"=v"(r):"v"(x));return r;}
#define LOG2(x) LOG2_(x)
#endif

#define DPP_UP   0x138   // wave_shr:1 (crosses rows; lane 0 -> bound)
#define DPP_DN   0x130   // wave_shl:1
#define ROW_SHR1 0x111   // row-confined
#define ROW_SHR2 0x112
#define BCAST15  0x142
#define BCAST31  0x143

template<int CTRL, int RMASK = 0xF>
static __device__ __forceinline__ float dppz(float v){   // invalid/masked -> 0
    return __int_as_float(__builtin_amdgcn_update_dpp(
        0, __float_as_int(v), CTRL, RMASK, 0xF, true));
}
template<int CTRL>
static __device__ __forceinline__ float dppc(float old, float v){ // invalid -> old
    return __int_as_float(__builtin_amdgcn_update_dpp(
        __float_as_int(old), __float_as_int(v), CTRL, 0xF, 0xF, false));
}

// decode: low 16 bits interpreted as f16 -> f32
static __device__ __forceinline__ float dec16(unsigned bits16){
    unsigned short us = (unsigned short)bits16;
    _Float16 h;
    __builtin_memcpy(&h, &us, 2);
    return (float)h;
}

// ---- one row step. Entry: Cp = scan output of row r-1; cA/cB = h0
// coefficients (h0(r) = cA*C + cB, k=0 uses shifted C); g/h2p = row r-1
// state; Rc = raw e5m2 dword of row r+1. Loads row r+2 at ldsB+vaddr+IMM.
template<int IMM>
static __device__ __forceinline__
void stepRow(const char* ldsB, const int vaddr,
             const float vA16, const float vA32,
             float& Cp, float (&cA)[3], float (&cB)[3],
             float (&g)[3], float (&h2p)[3],
             unsigned& Rc, const float oneE, float (&S)[3])
{
    // ---- on-path: Cp -> p2 -> scan -> Cn (13 hops) ----
    const float Cs  = dppz<DPP_UP>(Cp);
    const float h01 = fmaf(cA[1], Cp, cB[1]);
    const float h02 = fmaf(cA[2], Cp, cB[2]);
    const float h00 = fmaf(cA[0], Cs, cB[0]);
    const float U   = dppz<DPP_UP>(h02);           // h0(r, c-1) for k=0
    const float tp  = fmaf(K21, h00, K20 * h01);
    const float p2  = fmaf(K22, U, tp);            // lane-local h1 prefix top
    float t = dppz<DPP_UP>(p2);                    // exclusive pre-shift
    t = fmaf(SAW1, dppz<ROW_SHR1>(t), t);
    t = fmaf(SAW2, dppz<ROW_SHR2>(t), t);
    t = fmaf(vA16, dppz<BCAST15, 0xa>(t), t);      // rows 1,3 only (exact)
    const float Cn = fmaf(vA32, dppz<BCAST31>(t), t);

    // ---- off-path ----
    const unsigned Rn = *(const unsigned*)(ldsB + vaddr + IMM);   // row r+2
    const float D0 = dec16(Rc << 8);
    const float D1 = dec16(Rc & 0xFF00u);
    const float D2 = dec16((Rc >> 8) & 0xFF00u);
    const float D3 = dppz<DPP_DN>(D0);

    const float b0 = K20 * U;
    const float p1 = fmaf(K21, U, K20 * h00);
    const float h20 = fmaf(CGO, g[0], CGE * h2p[0]);
    const float h21 = fmaf(CGO, g[1], CGE * h2p[1]);
    const float h22 = fmaf(CGO, g[2], CGE * h2p[2]);
    const float Q0n = (h00 + b0) + h20;
    const float Q1n = (h01 + p1) + h21;
    const float Q2n = (h02 + p2) + h22;

    // score: hs_k = Qkn + CA_{k+1}*Cn ; x2 = (D1, D2, D3); zeros gate
    S[0] = fmaf(D1, fmaf(CA1, Cn, Q0n), S[0]);
    S[1] = fmaf(D2, fmaf(CA2, Cn, Q1n), S[1]);
    S[2] = fmaf(D3, fmaf(CA3, Cn, Q2n), S[2]);

    // g/h2 state for row r+1
    g[0] = h00 + fmaf(CA1, Cn, b0);
    g[1] = h01 + fmaf(CA2, Cn, p1);
    g[2] = h02 + fmaf(CA3, Cn, p2);
    h2p[0] = h20; h2p[1] = h21; h2p[2] = h22;

    // coefficients for row r+1: h0' = D'*(hs + oneE) in cA*C + cB form
    const float Q0 = Q0n + oneE;
    const float Q1 = Q1n + oneE;
    const float Q2 = Q2n + oneE;
    const float Q2s = dppc<DPP_UP>(oneE, Q2);      // lane0 boundary = oneE
    cA[0] = CA3 * D0;  cB[0] = D0 * Q2s;
    cA[1] = CA1 * D1;  cB[1] = D1 * Q0;
    cA[2] = CA2 * D2;  cB[2] = D2 * Q1;

    Rc = Rn;
    Cp = Cn;
}

__global__ __launch_bounds__(256)
void sw_fastrow(const float* __restrict__ x, float* __restrict__ part,
                float* __restrict__ out_atomic, int use_atomic) {
    const int b = blockIdx.x;
    const float* xb = x + (size_t)b * 22801;
    const int tid = threadIdx.x;

    __shared__ char ldsB[38912];   // 152 rows x 256B (row-major e5m2)

    // ---- phase A0: zero-init (all 4 waves) ----
    {
        int4* l4 = (int4*)ldsB;
        for (int i = tid; i < 38912 / 16; i += 256) l4[i] = int4{0,0,0,0};
    }
    __syncthreads();

    // ---- phase A1: coalesced load + exp -> e5m2 byte scatter ----
    for (int i = 0; i < 90; ++i) {
        const int idx = i * 256 + tid;
        const int idc = idx > 22800 ? 22800 : idx;
        const float v = EXP2(xb[idc] * L2E);
        const _Float16 hv = (_Float16)v;          // RNE f32->f16
        unsigned short u16; __builtin_memcpy(&u16, &hv, 2);
        const unsigned byte = ((unsigned)u16 + 0x7Fu + ((u16 >> 8) & 1u)) >> 8;
        const unsigned r = ((unsigned)idc * 111111u) >> 24;   // idc / 151
        const int c = idc - 151 * (int)r;
        const int l3 = (c * 0x5556) >> 16;        // c / 3
        const int kk = c - 3 * l3;
        ldsB[(int)r * 256 + 4 * l3 + kk] = (char)byte;
    }
    __syncthreads();
    if (tid >= 64) return;                        // waves 1-3 done

    // ---- phase B: DP on wave 0 ----
    const int lane = tid;
    const float vA16 = EXP2(-4.3280851226668902f * (float)((lane & 15) + 1));
    const float vA32 = EXP2(-4.3280851226668902f * (float)((lane & 31) + 1));
    const int vl4 = 4 * lane;

    float Cp = 0.0f;
    float cA[3], cB[3];
    {
        const unsigned w0 = *(const unsigned*)(ldsB + vl4);   // row 0
        cA[0] = 0.0f; cA[1] = 0.0f; cA[2] = 0.0f;
        cB[0] = dec16(w0 << 8);                   // h0(0) = sx*(0 + 1)
        cB[1] = dec16(w0 & 0xFF00u);
        cB[2] = dec16((w0 >> 8) & 0xFF00u);
    }
    unsigned Rc = *(const unsigned*)(ldsB + 256 + vl4);       // row 1
    float g[3]   = {0.0f, 0.0f, 0.0f};
    float h2p[3] = {0.0f, 0.0f, 0.0f};
    float S[3]   = {0.0f, 0.0f, 0.0f};
    float oneE = 1.0f;   // 2^-E
    float E = 0.0f;

    int vaddr = 512 + vl4;   // byte addr of row 2

    for (int gi = 0; gi < 18; ++gi) {   // rows 8gi .. 8gi+7
        stepRow<   0>(ldsB, vaddr, vA16, vA32, Cp, cA, cB, g, h2p, Rc, oneE, S);
        stepRow< 256>(ldsB, vaddr, vA16, vA32, Cp, cA, cB, g, h2p, Rc, oneE, S);
        stepRow< 512>(ldsB, vaddr, vA16, vA32, Cp, cA, cB, g, h2p, Rc, oneE, S);
        stepRow< 768>(ldsB, vaddr, vA16, vA32, Cp, cA, cB, g, h2p, Rc, oneE, S);
        stepRow<1024>(ldsB, vaddr, vA16, vA32, Cp, cA, cB, g, h2p, Rc, oneE, S);
        stepRow<1280>(ldsB, vaddr, vA16, vA32, Cp, cA, cB, g, h2p, Rc, oneE, S);
        stepRow<1536>(ldsB, vaddr, vA16, vA32, Cp, cA, cB, g, h2p, Rc, oneE, S);
        // renorm decision from row 8gi+6 state; applied after row 8gi+7.
        // RTHR=2^28, growth ~2^9.5/row, 1-row lag -> bounded << f32 max.
        float m = fmaxf(fmaxf(g[0], g[1]), g[2]);
        m = fmaxf(m, fmaxf(fmaxf(h2p[0], h2p[1]), h2p[2]));
        const bool rn = __any(m > RTHR);
        const float sc = rn ? RSC : 1.0f;
        stepRow<1792>(ldsB, vaddr, vA16, vA32, Cp, cA, cB, g, h2p, Rc, oneE, S);
        #pragma unroll
        for (int k = 0; k < 3; ++k) {
            cB[k] *= sc; g[k] *= sc; h2p[k] *= sc; S[k] *= sc;
        }
        Cp *= sc; oneE *= sc; E += rn ? EADD : 0.0f;
        vaddr += 2048;
    }
    // tail rows 144..149 (loads reach row 151 = zero pad)
    stepRow<   0>(ldsB, vaddr, vA16, vA32, Cp, cA, cB, g, h2p, Rc, oneE, S);
    stepRow< 256>(ldsB, vaddr, vA16, vA32, Cp, cA, cB, g, h2p, Rc, oneE, S);
    stepRow< 512>(ldsB, vaddr, vA16, vA32, Cp, cA, cB, g, h2p, Rc, oneE, S);
    stepRow< 768>(ldsB, vaddr, vA16, vA32, Cp, cA, cB, g, h2p, Rc, oneE, S);
    stepRow<1024>(ldsB, vaddr, vA16, vA32, Cp, cA, cB, g, h2p, Rc, oneE, S);
    stepRow<1280>(ldsB, vaddr, vA16, vA32, Cp, cA, cB, g, h2p, Rc, oneE, S);

    // wave sum of S (E uniform across lanes)
    float St = (S[0] + S[1]) + S[2];
    #pragma unroll
    for (int off = 32; off; off >>= 1) St += __shfl_xor(St, off, 64);
    if (lane == 0) {
        const float val = LN2 * (E + LOG2(St));
        if (use_atomic) atomicAdd(out_atomic, val);
        else            part[b] = val;
    }
}

__global__ __launch_bounds__(256)
void final_reduce(const float* __restrict__ part, float* __restrict__ out) {
    const int t = threadIdx.x;
    float v = part[t] + part[t + 256];
    #pragma unroll
    for (int off = 32; off; off >>= 1) v += __shfl_xor(v, off);
    __shared__ float ws[4];
    if ((t & 63) == 0) ws[t >> 6] = v;
    __syncthreads();
    if (t == 0) out[0] = ws[0] + ws[1] + ws[2] + ws[3];
}

extern "C" void kernel_launch(void* const* d_in, const int* in_sizes, int n_in,
                              void* d_out, int out_size, void* d_ws, size_t ws_size,
                              hipStream_t stream) {
    const float* x = (const float*)d_in[0];
    float* out = (float*)d_out;

    if (ws_size >= 512 * sizeof(float)) {
        float* part = (float*)d_ws;
        sw_fastrow<<<512, 256, 0, stream>>>(x, part, nullptr, 0);
        final_reduce<<<1, 256, 0, stream>>>(part, out);
    } else {
        hipMemsetAsync(out, 0, sizeof(float), stream);
        sw_fastrow<<<512, 256, 0, stream>>>(x, nullptr, out, 1);
    }
}

// Round 20
// 35.606 us; speedup vs baseline: 1.1249x; 1.1249x over previous
//
#include <hip/hip_runtime.h>

// Smith-Waterman soft-DP, B=512, x: (512,151,151) f32, scalar output.
// ROW-SCAN formulation (150 row iterations) — DP identical to the best-
// measured r17 variant (35.87us). h1's along-row recurrence solved by a
// weighted DPP prefix scan; h0/h2/score are prev-row FMAs. Lane packing
// c = 3*lane + k. Linear domain H = exp(h)*2^-E; x staged as e5m2 bytes,
// row-major [row][4*lane(+k)] in LDS.
// THIS ROUND: phase A software-pipelined (12 batches x 8 coalesced loads,
// ping-pong double buffer) so the load->use distance spans a full batch.
// 512 blocks x 256 threads; waves 1-3 stage then exit; wave 0 runs DP.

#define CGO 6.737946999085467e-03f   // e^-5
#define CGE 3.678794411714423e-01f   // e^-1
#define L2E 1.4426950408889634f
#define LN2 0.6931471805599453f
#define RTHR 0x1p28f
#define RSC  0x1p-64f
#define EADD 64.0f

// scan constants: A = e^-3 (per-lane carry factor, 3 cells/lane)
#define SA1 4.9787068367863944e-02f   // e^-3
#define SA2 2.4787521766663585e-03f   // e^-6
#define SA4 6.1442123533282098e-06f   // e^-12
#define SA8 3.7751345442790977e-11f   // e^-24
#define CA1 3.6787944117144233e-01f   // e^-1
#define CA2 1.3533528323661270e-01f   // e^-2
#define CA3 4.9787068367863944e-02f   // e^-3

#if __has_builtin(__builtin_amdgcn_exp2f)
#define EXP2(x) __builtin_amdgcn_exp2f(x)
#else
static __device__ __forceinline__ float EXP2_(float x){float r;asm("v_exp_f32 %0, %1":"=v"(r):"v"(x));return r;}
#define EXP2(x) EXP2_(x)
#endif

#if __has_builtin(__builtin_amdgcn_logf)
#define LOG2(x) __builtin_amdgcn_logf(x)
#else
static __device__ __forceinline__ float LOG2_(float x){float r;asm("v_log_f32 %0, %1":"=v"(r):"v"(x));return r;}
#define LOG2(x) LOG2_(x)
#endif

#define DPP_UP   0x138   // wave_shr:1 (lane i <- i-1; lane 0 -> 0)
#define DPP_DN   0x130   // wave_shl:1 (lane i <- i+1; lane 63 -> 0)
#define ROW_SHR1 0x111
#define ROW_SHR2 0x112
#define ROW_SHR4 0x114
#define ROW_SHR8 0x118
#define BCAST15  0x142
#define BCAST31  0x143

template<int CTRL>
static __device__ __forceinline__ float dppz(float v){   // invalid lanes -> 0
    return __int_as_float(__builtin_amdgcn_update_dpp(
        0, __float_as_int(v), CTRL, 0xF, 0xF, true));
}

// decode: low 16 bits interpreted as f16 -> f32
static __device__ __forceinline__ float dec16(unsigned bits16){
    unsigned short us = (unsigned short)bits16;
    _Float16 h;
    __builtin_memcpy(&h, &us, 2);
    return (float)h;
}

// ---- one row step (row r). Entry: SX[k] = exp(x[r, 3l+k]); Rc = raw e5m2
// dword of row r+1; HSs[k] = hs(r-1, c-1) (shifted); g[k] = (h0+h1)(r-1,c);
// h2p[k] = h2(r-1,c). Issues load of row r+2; x2 comes from decoding Rc.
template<int IMM>
static __device__ __forceinline__
void stepRow(const char* ldsB, const int vaddr,
             const float vA16, const float vA32,
             float (&SX)[3], unsigned& Rc,
             float (&HSs)[3], float (&g)[3], float (&h2p)[3],
             const float oneE, float (&S)[3])
{
    const unsigned Rn = *(const unsigned*)(ldsB + vaddr + IMM);  // row r+2
    // decode row r+1 (x2 for this row; sx for next row)
    const float D0 = dec16(Rc << 8);
    const float D1 = dec16(Rc & 0xFF00u);
    const float D2 = dec16((Rc >> 8) & 0xFF00u);
    const float D3 = dppz<DPP_DN>(D0);          // byte0 of lane+1

    // h0(r,c) = sx * (hs(r-1,c-1) + oneE)
    const float h00 = SX[0] * (HSs[0] + oneE);
    const float h01 = SX[1] * (HSs[1] + oneE);
    const float h02 = SX[2] * (HSs[2] + oneE);

    // b(c) = CGO * h0(r, c-1)
    const float h0u = dppz<DPP_UP>(h02);
    const float b0 = CGO * h0u;
    const float b1 = CGO * h00;
    const float b2 = CGO * h01;

    // local prefix within lane (cells k=0,1,2)
    const float p1 = fmaf(CGE, b0, b1);
    const float p2 = fmaf(CGE, p1, b2);

    // cross-lane exclusive weighted scan of lane totals (factor A=e^-3)
    float t = dppz<DPP_UP>(p2);
    t = fmaf(SA1, dppz<ROW_SHR1>(t), t);
    t = fmaf(SA2, dppz<ROW_SHR2>(t), t);
    t = fmaf(SA4, dppz<ROW_SHR4>(t), t);
    t = fmaf(SA8, dppz<ROW_SHR8>(t), t);
    t = fmaf(vA16, dppz<BCAST15>(t), t);
    t = fmaf(vA32, dppz<BCAST31>(t), t);

    // h1_k = p_k + CGE^{k+1} * C
    const float h10 = fmaf(CA1, t, b0);
    const float h11 = fmaf(CA2, t, p1);
    const float h12 = fmaf(CA3, t, p2);

    // h2(r,c) = CGO*(h0+h1)(r-1,c) + CGE*h2(r-1,c)
    const float h20 = fmaf(CGO, g[0], CGE * h2p[0]);
    const float h21 = fmaf(CGO, g[1], CGE * h2p[1]);
    const float h22 = fmaf(CGO, g[2], CGE * h2p[2]);

    // g = h0+h1; hs = g+h2
    g[0] = h00 + h10; g[1] = h01 + h11; g[2] = h02 + h12;
    const float hs0 = g[0] + h20;
    const float hs1 = g[1] + h21;
    const float hs2 = g[2] + h22;
    h2p[0] = h20; h2p[1] = h21; h2p[2] = h22;

    // score: x2(r,c) = exp(x[r+1, c+1]) = (D1, D2, D3); stored zeros gate
    S[0] = fmaf(D1, hs0, S[0]);
    S[1] = fmaf(D2, hs1, S[1]);
    S[2] = fmaf(D3, hs2, S[2]);

    // next-row prep
    HSs[0] = dppz<DPP_UP>(hs2);
    HSs[1] = hs0; HSs[2] = hs1;
    SX[0] = D0; SX[1] = D1; SX[2] = D2;
    Rc = Rn;
}

__global__ __launch_bounds__(256)
void sw_row(const float* __restrict__ x, float* __restrict__ part,
            float* __restrict__ out_atomic, int use_atomic) {
    const int b = blockIdx.x;
    const float* xb = x + (size_t)b * 22801;
    const int tid = threadIdx.x;

    __shared__ char ldsB[38912];   // 152 rows x 256B (row-major e5m2)

    // ---- phase A0: zero-init (all 4 waves) ----
    {
        int4* l4 = (int4*)ldsB;
        for (int i = tid; i < 38912 / 16; i += 256) l4[i] = int4{0,0,0,0};
    }
    __syncthreads();

    // ---- phase A1: pipelined load + exp -> e5m2 byte scatter ----
    // 12 batches x 8 coalesced loads/thread, ping-pong double buffer.
    {
        auto PROC = [&](float v, int idx) {
            const int idc = idx > 22800 ? 22800 : idx;
            const float e = EXP2(v * L2E);
            const _Float16 hv = (_Float16)e;      // RNE f32->f16
            unsigned short u16; __builtin_memcpy(&u16, &hv, 2);
            const unsigned byte = ((unsigned)u16 + 0x7Fu + ((u16 >> 8) & 1u)) >> 8;
            const unsigned r = ((unsigned)idc * 111111u) >> 24;   // idc / 151
            const int c = idc - 151 * (int)r;
            const int l3 = (c * 0x5556) >> 16;    // c / 3
            const int kk = c - 3 * l3;
            ldsB[(int)r * 256 + 4 * l3 + kk] = (char)byte;
        };
        float va[8], vb[8];
        #pragma unroll
        for (int j = 0; j < 8; ++j) {
            const int idx = j * 256 + tid;
            va[j] = xb[idx > 22800 ? 22800 : idx];
        }
        for (int i = 0; i < 12; i += 2) {
            if (i + 1 < 12) {
                #pragma unroll
                for (int j = 0; j < 8; ++j) {
                    const int idx = (i + 1) * 2048 + j * 256 + tid;
                    vb[j] = xb[idx > 22800 ? 22800 : idx];
                }
            }
            #pragma unroll
            for (int j = 0; j < 8; ++j) PROC(va[j], i * 2048 + j * 256 + tid);
            if (i + 2 < 12) {
                #pragma unroll
                for (int j = 0; j < 8; ++j) {
                    const int idx = (i + 2) * 2048 + j * 256 + tid;
                    va[j] = xb[idx > 22800 ? 22800 : idx];
                }
            }
            if (i + 1 < 12) {
                #pragma unroll
                for (int j = 0; j < 8; ++j) PROC(vb[j], (i + 1) * 2048 + j * 256 + tid);
            }
        }
    }
    __syncthreads();
    if (tid >= 64) return;                        // waves 1-3 done

    // ---- phase B: DP on wave 0 (identical to r17) ----
    const int lane = tid;
    const float vA16 = EXP2(-4.3280851226668902f * (float)((lane & 15) + 1));
    const float vA32 = EXP2(-4.3280851226668902f * (float)((lane & 31) + 1));
    const int vl4 = 4 * lane;

    float SX[3];
    unsigned Rc;
    {
        const unsigned w0 = *(const unsigned*)(ldsB + vl4);         // row 0
        SX[0] = dec16(w0 << 8);
        SX[1] = dec16(w0 & 0xFF00u);
        SX[2] = dec16((w0 >> 8) & 0xFF00u);
        Rc = *(const unsigned*)(ldsB + 256 + vl4);                  // row 1
    }
    float HSs[3] = {0.0f, 0.0f, 0.0f};
    float g[3]   = {0.0f, 0.0f, 0.0f};
    float h2p[3] = {0.0f, 0.0f, 0.0f};
    float S[3]   = {0.0f, 0.0f, 0.0f};
    float oneE = 1.0f;   // 2^-E
    float E = 0.0f;

    int vaddr = 512 + vl4;   // byte addr of row 2

    for (int gi = 0; gi < 18; ++gi) {   // rows 8gi .. 8gi+7
        stepRow<   0>(ldsB, vaddr, vA16, vA32, SX, Rc, HSs, g, h2p, oneE, S);
        stepRow< 256>(ldsB, vaddr, vA16, vA32, SX, Rc, HSs, g, h2p, oneE, S);
        stepRow< 512>(ldsB, vaddr, vA16, vA32, SX, Rc, HSs, g, h2p, oneE, S);
        stepRow< 768>(ldsB, vaddr, vA16, vA32, SX, Rc, HSs, g, h2p, oneE, S);
        stepRow<1024>(ldsB, vaddr, vA16, vA32, SX, Rc, HSs, g, h2p, oneE, S);
        stepRow<1280>(ldsB, vaddr, vA16, vA32, SX, Rc, HSs, g, h2p, oneE, S);
        stepRow<1536>(ldsB, vaddr, vA16, vA32, SX, Rc, HSs, g, h2p, oneE, S);
        // renorm decision from row 8gi+6 state; applied after row 8gi+7.
        // Safety: RTHR=2^28, worst growth ~2^8.2/row -> <=2^102 at apply.
        float m = fmaxf(fmaxf(g[0], g[1]), g[2]);
        m = fmaxf(m, fmaxf(fmaxf(h2p[0], h2p[1]), h2p[2]));
        const bool rn = __any(m > RTHR);
        const float sc = rn ? RSC : 1.0f;
        stepRow<1792>(ldsB, vaddr, vA16, vA32, SX, Rc, HSs, g, h2p, oneE, S);
        #pragma unroll
        for (int k = 0; k < 3; ++k) {
            HSs[k] *= sc; g[k] *= sc; h2p[k] *= sc; S[k] *= sc;
        }
        oneE *= sc; E += rn ? EADD : 0.0f;
        vaddr += 2048;
    }
    // tail rows 144..149 (loads reach row 151 = zero pad)
    stepRow<   0>(ldsB, vaddr, vA16, vA32, SX, Rc, HSs, g, h2p, oneE, S);
    stepRow< 256>(ldsB, vaddr, vA16, vA32, SX, Rc, HSs, g, h2p, oneE, S);
    stepRow< 512>(ldsB, vaddr, vA16, vA32, SX, Rc, HSs, g, h2p, oneE, S);
    stepRow< 768>(ldsB, vaddr, vA16, vA32, SX, Rc, HSs, g, h2p, oneE, S);
    stepRow<1024>(ldsB, vaddr, vA16, vA32, SX, Rc, HSs, g, h2p, oneE, S);
    stepRow<1280>(ldsB, vaddr, vA16, vA32, SX, Rc, HSs, g, h2p, oneE, S);

    // wave sum of S (E uniform across lanes)
    float St = (S[0] + S[1]) + S[2];
    #pragma unroll
    for (int off = 32; off; off >>= 1) St += __shfl_xor(St, off, 64);
    if (lane == 0) {
        const float val = LN2 * (E + LOG2(St));
        if (use_atomic) atomicAdd(out_atomic, val);
        else            part[b] = val;
    }
}

__global__ __launch_bounds__(256)
void final_reduce(const float* __restrict__ part, float* __restrict__ out) {
    const int t = threadIdx.x;
    float v = part[t] + part[t + 256];
    #pragma unroll
    for (int off = 32; off; off >>= 1) v += __shfl_xor(v, off);
    __shared__ float ws[4];
    if ((t & 63) == 0) ws[t >> 6] = v;
    __syncthreads();
    if (t == 0) out[0] = ws[0] + ws[1] + ws[2] + ws[3];
}

extern "C" void kernel_launch(void* const* d_in, const int* in_sizes, int n_in,
                              void* d_out, int out_size, void* d_ws, size_t ws_size,
                              hipStream_t stream) {
    const float* x = (const float*)d_in[0];
    float* out = (float*)d_out;

    if (ws_size >= 512 * sizeof(float)) {
        float* part = (float*)d_ws;
        sw_row<<<512, 256, 0, stream>>>(x, part, nullptr, 0);
        final_reduce<<<1, 256, 0, stream>>>(part, out);
    } else {
        hipMemsetAsync(out, 0, sizeof(float), stream);
        sw_row<<<512, 256, 0, stream>>>(x, nullptr, out, 1);
    }
}

// Round 21
// 32.086 us; speedup vs baseline: 1.2483x; 1.1097x over previous
//
#include <hip/hip_runtime.h>

// Smith-Waterman soft-DP, B=512, x: (512,151,151) f32, scalar output.
// ROW-SCAN formulation (150 row iterations; r17 structure). h1's along-row
// recurrence solved by a weighted DPP prefix scan (pre-shift + shr1 + shr2
// + bcast15 + bcast31; dropped shr4/shr8 carry weight <= e^-12). Lane
// packing c = 3*lane + k. Linear domain H = exp(h)*2^-E; x staged as f16
// in LDS, row-major [row][8B/lane] (152x512B = 76KB), ONE ds_read_b64/row.
// 512 blocks x 256 threads; waves 1-3 stage then exit; wave 0 runs DP.

#define CGO 6.737946999085467e-03f   // e^-5
#define CGE 3.678794411714423e-01f   // e^-1
#define L2E 1.4426950408889634f
#define LN2 0.6931471805599453f
#define RTHR 0x1p28f
#define RSC  0x1p-64f
#define EADD 64.0f

// scan constants: A = e^-3 (per-lane carry factor, 3 cells/lane)
#define SA1 4.9787068367863944e-02f   // e^-3
#define SA2 2.4787521766663585e-03f   // e^-6
#define CA1 3.6787944117144233e-01f   // e^-1
#define CA2 1.3533528323661270e-01f   // e^-2
#define CA3 4.9787068367863944e-02f   // e^-3

#if __has_builtin(__builtin_amdgcn_exp2f)
#define EXP2(x) __builtin_amdgcn_exp2f(x)
#else
static __device__ __forceinline__ float EXP2_(float x){float r;asm("v_exp_f32 %0, %1":"=v"(r):"v"(x));return r;}
#define EXP2(x) EXP2_(x)
#endif

#if __has_builtin(__builtin_amdgcn_logf)
#define LOG2(x) __builtin_amdgcn_logf(x)
#else
static __device__ __forceinline__ float LOG2_(float x){float r;asm("v_log_f32 %0, %1":"=v"(r):"v"(x));return r;}
#define LOG2(x) LOG2_(x)
#endif

#define DPP_UP   0x138   // wave_shr:1 (lane i <- i-1; lane 0 -> 0)
#define DPP_DN   0x130   // wave_shl:1 (lane i <- i+1; lane 63 -> 0)
#define ROW_SHR1 0x111
#define ROW_SHR2 0x112
#define BCAST15  0x142
#define BCAST31  0x143

template<int CTRL>
static __device__ __forceinline__ float dppz(float v){   // invalid lanes -> 0
    return __int_as_float(__builtin_amdgcn_update_dpp(
        0, __float_as_int(v), CTRL, 0xF, 0xF, true));
}

// decode: low 16 bits of w interpreted as f16 -> f32
static __device__ __forceinline__ float declo(unsigned w){
    unsigned short us = (unsigned short)w;
    _Float16 h;
    __builtin_memcpy(&h, &us, 2);
    return (float)h;
}

// ---- one row step (row r). Entry: SX[k] = exp(x[r, 3l+k]); Rc = f16 pair-
// dwords of row r+1; HSs[k] = hs(r-1, c-1) (shifted); g[k] = (h0+h1)(r-1,c);
// h2p[k] = h2(r-1,c). Issues load of row r+2; x2 comes from decoding Rc.
template<int IMM>
static __device__ __forceinline__
void stepRow(const char* ldsB, const int vaddr,
             const float vA16, const float vA32,
             float (&SX)[3], uint2& Rc,
             float (&HSs)[3], float (&g)[3], float (&h2p)[3],
             const float oneE, float (&S)[3])
{
    const uint2 Rn = *(const uint2*)(ldsB + vaddr + IMM);  // row r+2
    // decode row r+1 (x2 for this row; sx for next row)
    const float D0 = declo(Rc.x);
    const float D1 = declo(Rc.x >> 16);
    const float D2 = declo(Rc.y);
    const float D3 = dppz<DPP_DN>(D0);          // cell0 of lane+1

    // h0(r,c) = sx * (hs(r-1,c-1) + oneE)
    const float h00 = SX[0] * (HSs[0] + oneE);
    const float h01 = SX[1] * (HSs[1] + oneE);
    const float h02 = SX[2] * (HSs[2] + oneE);

    // b(c) = CGO * h0(r, c-1)
    const float h0u = dppz<DPP_UP>(h02);
    const float b0 = CGO * h0u;
    const float b1 = CGO * h00;
    const float b2 = CGO * h01;

    // local prefix within lane (cells k=0,1,2)
    const float p1 = fmaf(CGE, b0, b1);
    const float p2 = fmaf(CGE, p1, b2);

    // cross-lane exclusive weighted scan of lane totals (factor A=e^-3).
    // Coverage d=1..4 within 16-lane rows + exact boundary carries via
    // bcast15/31; dropped shr4/shr8 terms weigh <= A^4 = e^-12.
    float t = dppz<DPP_UP>(p2);
    t = fmaf(SA1, dppz<ROW_SHR1>(t), t);
    t = fmaf(SA2, dppz<ROW_SHR2>(t), t);
    t = fmaf(vA16, dppz<BCAST15>(t), t);
    t = fmaf(vA32, dppz<BCAST31>(t), t);

    // h1_k = p_k + CGE^{k+1} * C
    const float h10 = fmaf(CA1, t, b0);
    const float h11 = fmaf(CA2, t, p1);
    const float h12 = fmaf(CA3, t, p2);

    // h2(r,c) = CGO*(h0+h1)(r-1,c) + CGE*h2(r-1,c)
    const float h20 = fmaf(CGO, g[0], CGE * h2p[0]);
    const float h21 = fmaf(CGO, g[1], CGE * h2p[1]);
    const float h22 = fmaf(CGO, g[2], CGE * h2p[2]);

    // g = h0+h1; hs = g+h2
    g[0] = h00 + h10; g[1] = h01 + h11; g[2] = h02 + h12;
    const float hs0 = g[0] + h20;
    const float hs1 = g[1] + h21;
    const float hs2 = g[2] + h22;
    h2p[0] = h20; h2p[1] = h21; h2p[2] = h22;

    // score: x2(r,c) = exp(x[r+1, c+1]) = (D1, D2, D3); stored zeros gate
    S[0] = fmaf(D1, hs0, S[0]);
    S[1] = fmaf(D2, hs1, S[1]);
    S[2] = fmaf(D3, hs2, S[2]);

    // next-row prep
    HSs[0] = dppz<DPP_UP>(hs2);
    HSs[1] = hs0; HSs[2] = hs1;
    SX[0] = D0; SX[1] = D1; SX[2] = D2;
    Rc = Rn;
}

__global__ __launch_bounds__(256)
void sw_row(const float* __restrict__ x, float* __restrict__ part,
            float* __restrict__ out_atomic, int use_atomic) {
    const int b = blockIdx.x;
    const float* xb = x + (size_t)b * 22801;
    const int tid = threadIdx.x;

    __shared__ char ldsB[77824];   // 152 rows x 512B (row-major f16)

    // ---- phase A0: zero-init (all 4 waves) ----
    {
        int4* l4 = (int4*)ldsB;
        for (int i = tid; i < 77824 / 16; i += 256) l4[i] = int4{0,0,0,0};
    }
    __syncthreads();

    // ---- phase A1: pipelined load + exp -> f16 scatter ----
    // cell (r,c) -> byte r*512 + (c/3)*8 + (c%3)*2
    {
        auto PROC = [&](float v, int idx) {
            const int idc = idx > 22800 ? 22800 : idx;
            const _Float16 hv = (_Float16)EXP2(v * L2E);   // RNE f32->f16
            const unsigned r = ((unsigned)idc * 111111u) >> 24;   // idc / 151
            const int c = idc - 151 * (int)r;
            const int l3 = (c * 0x5556) >> 16;    // c / 3
            const int kk = c - 3 * l3;
            *(_Float16*)(ldsB + (int)r * 512 + l3 * 8 + kk * 2) = hv;
        };
        float va[8], vb[8];
        #pragma unroll
        for (int j = 0; j < 8; ++j) {
            const int idx = j * 256 + tid;
            va[j] = xb[idx > 22800 ? 22800 : idx];
        }
        for (int i = 0; i < 12; i += 2) {
            if (i + 1 < 12) {
                #pragma unroll
                for (int j = 0; j < 8; ++j) {
                    const int idx = (i + 1) * 2048 + j * 256 + tid;
                    vb[j] = xb[idx > 22800 ? 22800 : idx];
                }
            }
            #pragma unroll
            for (int j = 0; j < 8; ++j) PROC(va[j], i * 2048 + j * 256 + tid);
            if (i + 2 < 12) {
                #pragma unroll
                for (int j = 0; j < 8; ++j) {
                    const int idx = (i + 2) * 2048 + j * 256 + tid;
                    va[j] = xb[idx > 22800 ? 22800 : idx];
                }
            }
            if (i + 1 < 12) {
                #pragma unroll
                for (int j = 0; j < 8; ++j) PROC(vb[j], (i + 1) * 2048 + j * 256 + tid);
            }
        }
    }
    __syncthreads();
    if (tid >= 64) return;                        // waves 1-3 done

    // ---- phase B: DP on wave 0 ----
    const int lane = tid;
    const float vA16 = EXP2(-4.3280851226668902f * (float)((lane & 15) + 1));
    const float vA32 = EXP2(-4.3280851226668902f * (float)((lane & 31) + 1));
    const int vl8 = 8 * lane;

    float SX[3];
    uint2 Rc;
    {
        const uint2 w0 = *(const uint2*)(ldsB + vl8);               // row 0
        SX[0] = declo(w0.x);
        SX[1] = declo(w0.x >> 16);
        SX[2] = declo(w0.y);
        Rc = *(const uint2*)(ldsB + 512 + vl8);                     // row 1
    }
    float HSs[3] = {0.0f, 0.0f, 0.0f};
    float g[3]   = {0.0f, 0.0f, 0.0f};
    float h2p[3] = {0.0f, 0.0f, 0.0f};
    float S[3]   = {0.0f, 0.0f, 0.0f};
    float oneE = 1.0f;   // 2^-E
    float E = 0.0f;

    int vaddr = 1024 + vl8;   // byte addr of row 2

    for (int gi = 0; gi < 18; ++gi) {   // rows 8gi .. 8gi+7
        stepRow<   0>(ldsB, vaddr, vA16, vA32, SX, Rc, HSs, g, h2p, oneE, S);
        stepRow< 512>(ldsB, vaddr, vA16, vA32, SX, Rc, HSs, g, h2p, oneE, S);
        stepRow<1024>(ldsB, vaddr, vA16, vA32, SX, Rc, HSs, g, h2p, oneE, S);
        stepRow<1536>(ldsB, vaddr, vA16, vA32, SX, Rc, HSs, g, h2p, oneE, S);
        stepRow<2048>(ldsB, vaddr, vA16, vA32, SX, Rc, HSs, g, h2p, oneE, S);
        stepRow<2560>(ldsB, vaddr, vA16, vA32, SX, Rc, HSs, g, h2p, oneE, S);
        stepRow<3072>(ldsB, vaddr, vA16, vA32, SX, Rc, HSs, g, h2p, oneE, S);
        // renorm decision from row 8gi+6 state; applied after row 8gi+7.
        // g-only check is sufficient: h2 <= CGO/(1-CGE)*max_g = 0.011*g_max,
        // hs <= 1.011*g_max -> g crosses RTHR first (2^28; growth ~2^8/row).
        const float m = fmaxf(fmaxf(g[0], g[1]), g[2]);
        const bool rn = __any(m > RTHR);
        const float sc = rn ? RSC : 1.0f;
        stepRow<3584>(ldsB, vaddr, vA16, vA32, SX, Rc, HSs, g, h2p, oneE, S);
        #pragma unroll
        for (int k = 0; k < 3; ++k) {
            HSs[k] *= sc; g[k] *= sc; h2p[k] *= sc; S[k] *= sc;
        }
        oneE *= sc; E += rn ? EADD : 0.0f;
        vaddr += 4096;
    }
    // tail rows 144..149 (loads reach row 151 = zero pad)
    stepRow<   0>(ldsB, vaddr, vA16, vA32, SX, Rc, HSs, g, h2p, oneE, S);
    stepRow< 512>(ldsB, vaddr, vA16, vA32, SX, Rc, HSs, g, h2p, oneE, S);
    stepRow<1024>(ldsB, vaddr, vA16, vA32, SX, Rc, HSs, g, h2p, oneE, S);
    stepRow<1536>(ldsB, vaddr, vA16, vA32, SX, Rc, HSs, g, h2p, oneE, S);
    stepRow<2048>(ldsB, vaddr, vA16, vA32, SX, Rc, HSs, g, h2p, oneE, S);
    stepRow<2560>(ldsB, vaddr, vA16, vA32, SX, Rc, HSs, g, h2p, oneE, S);

    // wave sum of S (E uniform across lanes)
    float St = (S[0] + S[1]) + S[2];
    #pragma unroll
    for (int off = 32; off; off >>= 1) St += __shfl_xor(St, off, 64);
    if (lane == 0) {
        const float val = LN2 * (E + LOG2(St));
        if (use_atomic) atomicAdd(out_atomic, val);
        else            part[b] = val;
    }
}

__global__ __launch_bounds__(256)
void final_reduce(const float* __restrict__ part, float* __restrict__ out) {
    const int t = threadIdx.x;
    float v = part[t] + part[t + 256];
    #pragma unroll
    for (int off = 32; off; off >>= 1) v += __shfl_xor(v, off);
    __shared__ float ws[4];
    if ((t & 63) == 0) ws[t >> 6] = v;
    __syncthreads();
    if (t == 0) out[0] = ws[0] + ws[1] + ws[2] + ws[3];
}

extern "C" void kernel_launch(void* const* d_in, const int* in_sizes, int n_in,
                              void* d_out, int out_size, void* d_ws, size_t ws_size,
                              hipStream_t stream) {
    const float* x = (const float*)d_in[0];
    float* out = (float*)d_out;

    if (ws_size >= 512 * sizeof(float)) {
        float* part = (float*)d_ws;
        sw_row<<<512, 256, 0, stream>>>(x, part, nullptr, 0);
        final_reduce<<<1, 256, 0, stream>>>(part, out);
    } else {
        hipMemsetAsync(out, 0, sizeof(float), stream);
        sw_row<<<512, 256, 0, stream>>>(x, nullptr, out, 1);
    }
}